// Round 15
// baseline (2734.719 us; speedup 1.0000x reference)
//
#include <hip/hip_runtime.h>

typedef __attribute__((ext_vector_type(8))) short short8;
typedef __attribute__((ext_vector_type(4))) float f32x4;

#define MFMA16 __builtin_amdgcn_mfma_f32_16x16x32_bf16

__device__ __forceinline__ unsigned short f2bf(float f){
  union { float f; unsigned int u; } v; v.f = f;
  unsigned int u = v.u + 0x7fffu + ((v.u >> 16) & 1u);  // RNE
  return (unsigned short)(u >> 16);
}
__device__ __forceinline__ float lo2f(unsigned int u){ union { unsigned int u; float f; } v; v.u = u << 16; return v.f; }
__device__ __forceinline__ float hi2f(unsigned int u){ union { unsigned int u; float f; } v; v.u = u & 0xffff0000u; return v.f; }

// async global->LDS, 16B per lane (dest = base + lane*16, HW-defined)
__device__ __forceinline__ void load_lds16(const unsigned short* g, unsigned short* l){
  typedef const __attribute__((address_space(1))) unsigned int* gp_t;
  typedef __attribute__((address_space(3))) unsigned int* sp_t;
  __builtin_amdgcn_global_load_lds((gp_t)(const void*)g, (sp_t)(void*)l, 16, 0, 0);
}

// ---------------- ws layout (weights, elems) ----------------
constexpr size_t W1T_OFF  = 0;                               // 8 x [256][512]
constexpr size_t W1T_HSTR = 512*256;
constexpr size_t W2T_OFF  = W1T_OFF + 8*W1T_HSTR;            // 8 x [256][256]
constexpr size_t W2T_HSTR = 256*256;
constexpr size_t OQKV_OFF = W2T_OFF + 8*W2T_HSTR;            // [768][2048]
constexpr size_t OW1_OFF  = OQKV_OFF + (size_t)768*2048;     // [256][2304]
constexpr size_t OW2_OFF  = OW1_OFF + (size_t)256*2304;      // [256][256]
constexpr size_t WQC_OFF  = OW2_OFF + (size_t)256*256;       // 8 x [256][256] bf16 cast
constexpr size_t WKC_OFF  = WQC_OFF + (size_t)8*65536;
constexpr size_t WVC_OFF  = WKC_OFF + (size_t)8*65536;
constexpr size_t MT_OFF   = WVC_OFF + (size_t)8*65536;       // 8 x [256][256]: MT[m][i] = sum_j Wk[m][j]Wq[i][j]
constexpr size_t PT_OFF   = MT_OFF + (size_t)8*65536;        // 8 x [256][256]: PT[j][m] = sum_d Wv[m][d]W1a[d][j]
constexpr size_t WT_ELEMS = PT_OFF + (size_t)8*65536;
constexpr size_t XP_OFFB  = (WT_ELEMS*2 + 255) & ~(size_t)255;
constexpr size_t XP_BYTES = (size_t)131072*256*2;            // xp: row-major [BT][256]
constexpr size_t FEATS_OFFB = XP_OFFB + XP_BYTES;

constexpr int LDX  = 264;   // xs tile stride (528B -> bank step 4, 2-way free)
constexpr int LDQ  = 264;   // qs tile stride (G -> axp region, 256 cols)

// ---------------- prep: transpose weights to bf16 [N][K] ----------------
__global__ void k_transpose(const float* __restrict__ src, unsigned short* __restrict__ dst,
                            int K, int N, long long srcStride, long long dstStride){
  const int i = blockIdx.x*256 + threadIdx.x;
  const int b = blockIdx.y;
  const int n = i / K, k = i - n*K;
  dst[(size_t)b*dstStride + i] = f2bf(src[(size_t)b*srcStride + (size_t)k*N + n]);
}

// ---------------- prep: plain bf16 cast (keeps orientation) ----------------
__global__ void k_cast(const float* __restrict__ src, unsigned short* __restrict__ dst){
  const size_t i = ((size_t)blockIdx.x*256 + threadIdx.x) * 4;
  float4 a = *(const float4*)(src + i);
  dst[i+0] = f2bf(a.x); dst[i+1] = f2bf(a.y); dst[i+2] = f2bf(a.z); dst[i+3] = f2bf(a.w);
}

// ---------------- xp = bf16(x + pos), row-major ----------------
__global__ void k_xp(const float* __restrict__ x, const float* __restrict__ pos,
                     unsigned short* __restrict__ xp){
  const size_t i = ((size_t)blockIdx.x*256 + threadIdx.x) * 8;
  const int colb = (int)(i & 255);
  const int t = (int)((i >> 8) & 7);
  float4 a0 = *(const float4*)(x + i);
  float4 a1 = *(const float4*)(x + i + 4);
  float4 p0 = *(const float4*)(pos + t*256 + colb);
  float4 p1 = *(const float4*)(pos + t*256 + colb + 4);
  short8 o;
  o[0]=(short)f2bf(a0.x+p0.x); o[1]=(short)f2bf(a0.y+p0.y);
  o[2]=(short)f2bf(a0.z+p0.z); o[3]=(short)f2bf(a0.w+p0.w);
  o[4]=(short)f2bf(a1.x+p1.x); o[5]=(short)f2bf(a1.y+p1.y);
  o[6]=(short)f2bf(a1.z+p1.z); o[7]=(short)f2bf(a1.w+p1.w);
  *(short8*)(xp + i) = o;
}

// ==================== per-head fused kernel (factored G/axp, 67.6KB LDS -> 2 blk/CU) ====================
// Region lifecycle: xs = xp -> h1 ; qs = G -> axp (in-place per-wave overwrite).
__global__ __launch_bounds__(512, 4) void k_head(
    const unsigned short* __restrict__ xp,
    const unsigned short* __restrict__ WT,
    const float* __restrict__ hb1, const float* __restrict__ hb2,
    unsigned short* __restrict__ feats)
{
  __shared__ __align__(16) unsigned short xs[64*LDX];   // xp -> h1
  __shared__ __align__(16) unsigned short qs[64*LDQ];   // G -> axp

  const int h    = blockIdx.y;
  const int r0   = blockIdx.x << 6;
  const int tid  = threadIdx.x;
  const int wave = tid >> 6;
  const int lane = tid & 63;
  const int l16  = lane & 15;
  const int lq   = lane >> 4;

  // load xp tile (64 x 256)
  {
    const int row = tid >> 3, c0 = (tid & 7) << 5;
    const short8* s = (const short8*)(xp + (size_t)(r0 + row)*256 + c0);
    short8* d = (short8*)(xs + row*LDX + c0);
    #pragma unroll
    for (int j = 0; j < 4; j++) d[j] = s[j];
  }
  __syncthreads();

  // P1: G = xp @ MT^T  [64,256]@[256,256]; wave owns 32 cols
  {
    const unsigned short* Bm = WT + MT_OFF + (size_t)h*65536;
    f32x4 acc[4][2];
    #pragma unroll
    for (int m = 0; m < 4; m++){ acc[m][0] = (f32x4){0.f,0.f,0.f,0.f}; acc[m][1] = (f32x4){0.f,0.f,0.f,0.f}; }
    #pragma unroll
    for (int kk = 0; kk < 8; kk++){
      const int ko = (kk << 5) + (lq << 3);
      short8 a[4];
      #pragma unroll
      for (int m = 0; m < 4; m++)
        a[m] = *(const short8*)(xs + (m*16 + l16)*LDX + ko);
      #pragma unroll
      for (int n = 0; n < 2; n++){
        const int col = (wave << 5) + (n << 4) + l16;
        short8 b = *(const short8*)(Bm + (size_t)col*256 + ko);
        #pragma unroll
        for (int m = 0; m < 4; m++)
          acc[m][n] = MFMA16(a[m], b, acc[m][n], 0, 0, 0);
      }
    }
    #pragma unroll
    for (int n = 0; n < 2; n++){
      const int col = (wave << 5) + (n << 4) + l16;
      #pragma unroll
      for (int m = 0; m < 4; m++)
        #pragma unroll
        for (int r = 0; r < 4; r++)
          qs[(m*16 + lq*4 + r)*LDQ + col] = f2bf(acc[m][n][r]);
    }
  }
  __syncthreads();

  // P2+P3 fused: scores + softmax (lane=(t,s)); axp overwrites G in place.
  // Wave w only reads G rows w*8+t and only writes axp rows w*8+t; LDS ops are
  // program-ordered within a wave, so no barrier is needed for the overwrite.
  {
    const int t = lane >> 3, s = lane & 7;
    const unsigned short* Qr = qs + (wave*8 + t)*LDQ;        // G row (own wave)
    const unsigned short* Kr = xs + (wave*8 + s)*LDX;        // xp row
    float e0 = 0.f, e1 = 0.f, e2 = 0.f, e3 = 0.f;
    #pragma unroll
    for (int c = 0; c < 256; c += 8){
      union { short8 v; unsigned int u[4]; } qa, kb;
      qa.v = *(const short8*)(Qr + c);
      kb.v = *(const short8*)(Kr + c);
      e0 = fmaf(lo2f(qa.u[0]), lo2f(kb.u[0]), e0);
      e1 = fmaf(hi2f(qa.u[0]), hi2f(kb.u[0]), e1);
      e2 = fmaf(lo2f(qa.u[1]), lo2f(kb.u[1]), e2);
      e3 = fmaf(hi2f(qa.u[1]), hi2f(kb.u[1]), e3);
      e0 = fmaf(lo2f(qa.u[2]), lo2f(kb.u[2]), e0);
      e1 = fmaf(hi2f(qa.u[2]), hi2f(kb.u[2]), e1);
      e2 = fmaf(lo2f(qa.u[3]), lo2f(kb.u[3]), e2);
      e3 = fmaf(hi2f(qa.u[3]), hi2f(kb.u[3]), e3);
    }
    float e = (e0 + e1) + (e2 + e3);
    e *= 0.0625f;                    // 1/sqrt(256)
    if (s > t) e = -1e30f;           // causal
    float mx = fmaxf(e, __shfl_xor(e, 1));
    mx = fmaxf(mx, __shfl_xor(mx, 2));
    mx = fmaxf(mx, __shfl_xor(mx, 4));
    float p = (s <= t) ? __expf(e - mx) : 0.f;
    float sum = p;
    sum += __shfl_xor(sum, 1);
    sum += __shfl_xor(sum, 2);
    sum += __shfl_xor(sum, 4);
    const float pn = p / sum;        // lane (t,s) holds P[t][s]

    // axp = attn @ xp -> qs cols 0-255 (over G, own-wave rows); c8 = s
    const int c8 = s;
    float o[32];
    #pragma unroll
    for (int j = 0; j < 32; j++) o[j] = 0.f;
    #pragma unroll
    for (int ss = 0; ss < 8; ss++){
      const float w = __shfl(pn, (lane & 56) + ss);
      const unsigned short* Vr = xs + (wave*8 + ss)*LDX + (c8 << 5);
      #pragma unroll
      for (int jj = 0; jj < 4; jj++){
        union { short8 v; unsigned int u[4]; } vv;
        vv.v = *(const short8*)(Vr + jj*8);
        #pragma unroll
        for (int q = 0; q < 4; q++){
          o[jj*8 + 2*q]     = fmaf(w, lo2f(vv.u[q]), o[jj*8 + 2*q]);
          o[jj*8 + 2*q + 1] = fmaf(w, hi2f(vv.u[q]), o[jj*8 + 2*q + 1]);
        }
      }
    }
    unsigned short* Or = qs + (wave*8 + t)*LDQ + (c8 << 5);
    #pragma unroll
    for (int j = 0; j < 32; j++) Or[j] = f2bf(o[j]);
  }
  __syncthreads();

  // P4: h1 = relu([axp | xp] @ [PT | W1b]^T + b1); acc in regs, then h1 -> xs
  {
    const unsigned short* Bp = WT + PT_OFF + (size_t)h*65536;       // [256][256], k<256
    const unsigned short* B1 = WT + W1T_OFF + (size_t)h*W1T_HSTR;   // [256][512], k in [256,512)
    f32x4 acc[4][2];
    #pragma unroll
    for (int m = 0; m < 4; m++){ acc[m][0] = (f32x4){0.f,0.f,0.f,0.f}; acc[m][1] = (f32x4){0.f,0.f,0.f,0.f}; }
    #pragma unroll
    for (int kk = 0; kk < 16; kk++){
      const int ko = (kk << 5) + (lq << 3);
      short8 a[4];
      #pragma unroll
      for (int m = 0; m < 4; m++)
        a[m] = (kk < 8) ? *(const short8*)(qs + (m*16 + l16)*LDQ + ko)
                        : *(const short8*)(xs + (m*16 + l16)*LDX + (ko - 256));
      #pragma unroll
      for (int n = 0; n < 2; n++){
        const int col = (wave << 5) + (n << 4) + l16;
        short8 b = (kk < 8) ? *(const short8*)(Bp + (size_t)col*256 + ko)
                            : *(const short8*)(B1 + (size_t)col*512 + ko);
        #pragma unroll
        for (int m = 0; m < 4; m++)
          acc[m][n] = MFMA16(a[m], b, acc[m][n], 0, 0, 0);
      }
    }
    __syncthreads();   // all xs (xp) reads done -> safe to overwrite with h1
    #pragma unroll
    for (int n = 0; n < 2; n++){
      const int col = (wave << 5) + (n << 4) + l16;
      const float bv = hb1[(h << 8) + col];
      #pragma unroll
      for (int m = 0; m < 4; m++)
        #pragma unroll
        for (int r = 0; r < 4; r++)
          xs[(m*16 + lq*4 + r)*LDX + col] = f2bf(fmaxf(acc[m][n][r] + bv, 0.f));
    }
  }
  __syncthreads();

  // P5: feats_h = h1 @ W2T^T + b2 (h1 in xs)
  {
    const unsigned short* W = WT + W2T_OFF + (size_t)h * W2T_HSTR;
    f32x4 acc[4][2];
    #pragma unroll
    for (int m = 0; m < 4; m++){ acc[m][0] = (f32x4){0.f,0.f,0.f,0.f}; acc[m][1] = (f32x4){0.f,0.f,0.f,0.f}; }
    #pragma unroll
    for (int kk = 0; kk < 8; kk++){
      const int ko = (kk << 5) + (lq << 3);
      short8 a[4];
      #pragma unroll
      for (int m = 0; m < 4; m++)
        a[m] = *(const short8*)(xs + (m*16 + l16)*LDX + ko);
      #pragma unroll
      for (int n = 0; n < 2; n++){
        const int col = (wave << 5) + (n << 4) + l16;
        short8 b = *(const short8*)(W + (size_t)col*256 + ko);
        #pragma unroll
        for (int m = 0; m < 4; m++)
          acc[m][n] = MFMA16(a[m], b, acc[m][n], 0, 0, 0);
      }
    }
    #pragma unroll
    for (int n = 0; n < 2; n++){
      const int col = (wave << 5) + (n << 4) + l16;
      const float bv = hb2[(h << 8) + col];
      #pragma unroll
      for (int m = 0; m < 4; m++)
        #pragma unroll
        for (int r = 0; r < 4; r++)
          feats[(size_t)(r0 + m*16 + lq*4 + r)*2048 + (h << 8) + col] = f2bf(acc[m][n][r] + bv);
    }
  }
}

// ==================== output-layer attention ====================
__global__ __launch_bounds__(512, 4) void k_attn2(
    const unsigned short* __restrict__ qkv2, unsigned short* __restrict__ ao)
{
  __shared__ float aw[8][64];
  const int r0   = blockIdx.x * 64;
  const int tid  = threadIdx.x;
  const int wave = tid >> 6;
  const int lane = tid & 63;
  const int g = wave;
  {
    const int t = lane >> 3, s = lane & 7;
    const unsigned short* Qr = qkv2 + (size_t)(r0 + g*8 + t)*768;
    const unsigned short* Kr = qkv2 + (size_t)(r0 + g*8 + s)*768 + 256;
    float e0 = 0.f, e1 = 0.f, e2 = 0.f, e3 = 0.f;
    #pragma unroll
    for (int c = 0; c < 256; c += 8){
      union { short8 v; unsigned int u[4]; } qa, kb;
      qa.v = *(const short8*)(Qr + c);
      kb.v = *(const short8*)(Kr + c);
      e0 = fmaf(lo2f(qa.u[0]), lo2f(kb.u[0]), e0);
      e1 = fmaf(hi2f(qa.u[0]), hi2f(kb.u[0]), e1);
      e2 = fmaf(lo2f(qa.u[1]), lo2f(kb.u[1]), e2);
      e3 = fmaf(hi2f(qa.u[1]), hi2f(kb.u[1]), e3);
      e0 = fmaf(lo2f(qa.u[2]), lo2f(kb.u[2]), e0);
      e1 = fmaf(hi2f(qa.u[2]), hi2f(kb.u[2]), e1);
      e2 = fmaf(lo2f(qa.u[3]), lo2f(kb.u[3]), e2);
      e3 = fmaf(hi2f(qa.u[3]), hi2f(kb.u[3]), e3);
    }
    float e = (e0 + e1) + (e2 + e3);
    e *= 0.0625f;
    if (s > t) e = -1e30f;
    float mx = fmaxf(e, __shfl_xor(e, 1));
    mx = fmaxf(mx, __shfl_xor(mx, 2));
    mx = fmaxf(mx, __shfl_xor(mx, 4));
    float p = (s <= t) ? __expf(e - mx) : 0.f;
    float sum = p;
    sum += __shfl_xor(sum, 1);
    sum += __shfl_xor(sum, 2);
    sum += __shfl_xor(sum, 4);
    aw[g][lane] = p / sum;
  }
  __syncthreads();
  {
    const int t = lane >> 3, c8 = lane & 7;
    float o[32];
    #pragma unroll
    for (int j = 0; j < 32; j++) o[j] = 0.f;
    #pragma unroll
    for (int s = 0; s < 8; s++){
      const float w = aw[g][t*8 + s];
      const unsigned short* Vr = qkv2 + (size_t)(r0 + g*8 + s)*768 + 512 + (c8 << 5);
      #pragma unroll
      for (int jj = 0; jj < 4; jj++){
        union { short8 v; unsigned int u[4]; } vv;
        vv.v = *(const short8*)(Vr + jj*8);
        #pragma unroll
        for (int q = 0; q < 4; q++){
          o[jj*8 + 2*q]     = fmaf(w, lo2f(vv.u[q]), o[jj*8 + 2*q]);
          o[jj*8 + 2*q + 1] = fmaf(w, hi2f(vv.u[q]), o[jj*8 + 2*q + 1]);
        }
      }
    }
    unsigned short* Or = ao + (size_t)(r0 + g*8 + t)*256 + (c8 << 5);
    #pragma unroll
    for (int jj = 0; jj < 4; jj++){
      short8 v;
      #pragma unroll
      for (int q = 0; q < 8; q++) v[q] = (short)f2bf(o[jj*8 + q]);
      *(short8*)(Or + jj*8) = v;
    }
  }
}

// ==================== grouped tiled GEMM with global_load_lds staging ====================
// C_h[M,N] = A_h @ B_h^T. blockIdx.y = h*tilesN + ntile. 128x128 tile, 4 waves,
// BK=64, double-buffered LDS via async global->LDS (linear dest, swizzled source,
// XOR-swizzled frag reads). EPI: 0 = bf16; 1 = bias+relu bf16; 2 = bias f32.
template<int EPI>
__global__ __launch_bounds__(256, 2) void k_gemmg(
    const unsigned short* __restrict__ A1, long long lda1, int K1, long long a1hstr,
    const unsigned short* __restrict__ A2, long long lda2,
    const unsigned short* __restrict__ B, long long ldb, int K, long long bhstr,
    const float* __restrict__ bias, long long biashstr,
    void* __restrict__ Cv, long long ldc, long long chstr,
    int tilesN)
{
  __shared__ __align__(16) unsigned short SM[36864];   // A dbuf 32KB | B dbuf 32KB | (epilogue reuse)
  unsigned short* As = SM;            // [2][8192] elems, linear [128][64] per buf
  unsigned short* Bs = SM + 16384;    // [2][8192]

  const int h  = blockIdx.y / tilesN;
  const int c0 = (blockIdx.y - h*tilesN) * 128;
  A1 += (size_t)h * a1hstr;
  B  += (size_t)h * bhstr;

  const int tid  = threadIdx.x;
  const int wave = tid >> 6, lane = tid & 63;
  const int l16  = lane & 15, lq = lane >> 4;
  const int wm   = wave >> 1, wn = wave & 1;
  const size_t r0 = (size_t)blockIdx.x * 128;

  const int lrow = lane >> 3;                      // 0..7
  const int lcol = ((lane & 7) ^ lrow) << 3;       // swizzled source col (elems)
  const int axor = (l16 & 7) << 3;                 // frag-read XOR (elems)

  f32x4 acc[4][4];
  #pragma unroll
  for (int m = 0; m < 4; m++)
    #pragma unroll
    for (int n = 0; n < 4; n++) acc[m][n] = (f32x4){0.f,0.f,0.f,0.f};

  const int KS = K >> 6;

  // stage one 128x64 A-tile + B-tile into buf (16 x 1KB wave-calls each)
  auto stage = [&](int buf, int k0){
    #pragma unroll
    for (int jj = 0; jj < 4; jj++){
      const int c = wave*4 + jj;                   // chunk 0..15 (8 rows each)
      const int row = c*8 + lrow;
      const unsigned short* ga;
      if (k0 < K1) ga = A1 + (r0 + row)*lda1 + k0 + lcol;
      else         ga = A2 + (r0 + row)*lda2 + (k0 - K1) + lcol;
      load_lds16(ga, As + buf*8192 + c*512);
      const unsigned short* gb = B + (size_t)(c0 + row)*ldb + k0 + lcol;
      load_lds16(gb, Bs + buf*8192 + c*512);
    }
  };

  stage(0, 0);
  __syncthreads();   // drains vmcnt

  int cur = 0;
  for (int s2 = 0; s2 < KS; s2++){
    if (s2 + 1 < KS) stage(cur^1, (s2 + 1) << 6);  // async, in flight under MFMAs
    const unsigned short* Ab = As + cur*8192;
    const unsigned short* Bb = Bs + cur*8192;
    #pragma unroll
    for (int kk = 0; kk < 2; kk++){
      const int cb = (kk << 5) + (lq << 3);
      short8 af[4], bf[4];
      #pragma unroll
      for (int m = 0; m < 4; m++)
        af[m] = *(const short8*)(Ab + (wm*64 + m*16 + l16)*64 + (cb ^ axor));
      #pragma unroll
      for (int n = 0; n < 4; n++)
        bf[n] = *(const short8*)(Bb + (wn*64 + n*16 + l16)*64 + (cb ^ axor));
      #pragma unroll
      for (int n = 0; n < 4; n++)
        #pragma unroll
        for (int m = 0; m < 4; m++)
          acc[m][n] = MFMA16(af[m], bf[n], acc[m][n], 0,0,0);
    }
    __syncthreads();   // drains prefetch + guards buf swap
    cur ^= 1;
  }

  // epilogue: stage C in LDS, coalesced write
  if (EPI == 2){
    float* Cs = (float*)SM;           // [128][130] f32
    float* C = (float*)Cv + (size_t)h * chstr;
    #pragma unroll
    for (int n = 0; n < 4; n++){
      const int col = wn*64 + n*16 + l16;
      const float bv = bias[(size_t)h*biashstr + c0 + col];
      #pragma unroll
      for (int m = 0; m < 4; m++)
        #pragma unroll
        for (int r = 0; r < 4; r++)
          Cs[(wm*64 + m*16 + lq*4 + r)*130 + col] = acc[m][n][r] + bv;
    }
    __syncthreads();
    #pragma unroll
    for (int it = 0; it < 16; it++){
      const int idx = it*256 + tid;
      const int row = idx >> 5, c4 = (idx & 31) << 2;
      *(float4*)(C + (r0 + row)*ldc + c0 + c4) = *(const float4*)(Cs + row*130 + c4);
    }
  } else {
    unsigned short* Cs = SM;          // [128][132] bf16
    unsigned short* C = (unsigned short*)Cv + (size_t)h * chstr;
    #pragma unroll
    for (int n = 0; n < 4; n++){
      const int col = wn*64 + n*16 + l16;
      const float bv = (EPI == 1) ? bias[(size_t)h*biashstr + c0 + col] : 0.f;
      #pragma unroll
      for (int m = 0; m < 4; m++)
        #pragma unroll
        for (int r = 0; r < 4; r++){
          float v = acc[m][n][r] + bv;
          if (EPI == 1) v = fmaxf(v, 0.f);
          Cs[(wm*64 + m*16 + lq*4 + r)*132 + col] = f2bf(v);
        }
    }
    __syncthreads();
    #pragma unroll
    for (int it = 0; it < 8; it++){
      const int idx = it*256 + tid;
      const int row = idx >> 4, c8 = (idx & 15) << 3;
      *(short8*)(C + (r0 + row)*ldc + c0 + c8) = *(const short8*)(Cs + row*132 + c8);
    }
  }
}

extern "C" void kernel_launch(void* const* d_in, const int* in_sizes, int n_in,
                              void* d_out, int out_size, void* d_ws, size_t ws_size,
                              hipStream_t stream) {
  (void)n_in; (void)out_size;
  const float* x    = (const float*)d_in[0];
  const float* pos  = (const float*)d_in[1];
  const float* hWq  = (const float*)d_in[2];
  const float* hWk  = (const float*)d_in[3];
  const float* hWv  = (const float*)d_in[4];
  const float* hW1  = (const float*)d_in[5];
  const float* hb1  = (const float*)d_in[6];
  const float* hW2  = (const float*)d_in[7];
  const float* hb2  = (const float*)d_in[8];
  const float* oWq  = (const float*)d_in[9];
  const float* oWk  = (const float*)d_in[10];
  const float* oWv  = (const float*)d_in[11];
  const float* oW1  = (const float*)d_in[12];
  const float* ob1  = (const float*)d_in[13];
  const float* oW2  = (const float*)d_in[14];
  const float* ob2  = (const float*)d_in[15];

  unsigned short* WT  = (unsigned short*)d_ws;
  unsigned short* xp  = (unsigned short*)((char*)d_ws + XP_OFFB);
  float* out = (float*)d_out;

  const long long BT = in_sizes[0] / 256;   // 131072

  // chunk sizing: feats + qkv2 + ao + h1 rings = R*6656 bytes; keep L3-resident
  const size_t capB = (ws_size > FEATS_OFFB) ? (ws_size - FEATS_OFFB) : 0;
  long long R = (long long)(capB / 6656);
  if (R > 16384) R = 16384;
  if (R > BT) R = BT;
  R &= ~127LL;
  if (R < 128) R = 128;

  unsigned short* feats = (unsigned short*)((char*)d_ws + FEATS_OFFB);
  unsigned short* qkv2  = (unsigned short*)((char*)feats + (size_t)R*4096);
  unsigned short* ao    = (unsigned short*)((char*)qkv2  + (size_t)R*1536);
  unsigned short* h1o   = (unsigned short*)((char*)ao    + (size_t)R*512);

  // ---- prep: transposes, casts, weight-product GEMMs ----
  k_transpose<<<dim3(512,8),  256, 0, stream>>>(hW1, WT + W1T_OFF,            512, 256, 131072, 131072);
  k_transpose<<<dim3(256,8),  256, 0, stream>>>(hW2, WT + W2T_OFF,            256, 256, 65536, 65536);
  k_transpose<<<dim3(2048,1), 256, 0, stream>>>(oWq, WT + OQKV_OFF,           2048, 256, 0, 0);
  k_transpose<<<dim3(2048,1), 256, 0, stream>>>(oWk, WT + OQKV_OFF + 524288,  2048, 256, 0, 0);
  k_transpose<<<dim3(2048,1), 256, 0, stream>>>(oWv, WT + OQKV_OFF + 1048576, 2048, 256, 0, 0);
  k_transpose<<<dim3(2304,1), 256, 0, stream>>>(oW1, WT + OW1_OFF,            2304, 256, 0, 0);
  k_transpose<<<dim3(256,1),  256, 0, stream>>>(oW2, WT + OW2_OFF,            256, 256, 0, 0);
  k_cast<<<512, 256, 0, stream>>>(hWq, WT + WQC_OFF);
  k_cast<<<512, 256, 0, stream>>>(hWk, WT + WKC_OFF);
  k_cast<<<512, 256, 0, stream>>>(hWv, WT + WVC_OFF);

  // MT_h[m][i] = sum_j Wk[m][j] Wq[i][j]
  k_gemmg<0><<<dim3(2, 16), 256, 0, stream>>>(
      WT + WKC_OFF, 256, 1<<30, 65536, WT + WKC_OFF, 256,
      WT + WQC_OFF, 256, 256, 65536, nullptr, 0,
      WT + MT_OFF, 256, 65536, 2);

  // PT_h[j][m] = sum_d W1a[d][j] Wv[m][d]
  k_gemmg<0><<<dim3(2, 16), 256, 0, stream>>>(
      WT + W1T_OFF, 512, 1<<30, W1T_HSTR, WT + W1T_OFF, 512,
      WT + WVC_OFF, 256, 256, 65536, nullptr, 0,
      WT + PT_OFF, 256, 65536, 2);

  k_xp<<<(int)(BT/8), 256, 0, stream>>>(x, pos, xp);

  for (long long base = 0; base < BT; base += R) {
    const long long Rc = (BT - base < R) ? (BT - base) : R;
    const int mt64  = (int)(Rc / 64);
    const int mt128 = (int)(Rc / 128);

    k_head<<<dim3(mt64, 8), 512, 0, stream>>>(xp + base*256, WT, hb1, hb2, feats);

    // QKV2: A = feats [R][2048], K=2048
    k_gemmg<0><<<dim3(mt128, 6), 256, 0, stream>>>(
        feats, 2048, 1<<30, 0, feats, 2048,
        WT + OQKV_OFF, 2048, 2048, 0, nullptr, 0, qkv2, 768, 0, 6);

    k_attn2<<<mt64, 512, 0, stream>>>(qkv2, ao);

    // FFN1o: A = [ao | feats], K=2304
    k_gemmg<1><<<dim3(mt128, 2), 256, 0, stream>>>(
        ao, 256, 256, 0, feats, 2048,
        WT + OW1_OFF, 2304, 2304, 0, ob1, 0, h1o, 256, 0, 2);

    // FFN2o: A = h1o, K=256
    k_gemmg<2><<<dim3(mt128, 2), 256, 0, stream>>>(
        h1o, 256, 1<<30, 0, h1o, 256,
        WT + OW2_OFF, 256, 256, 0, ob2, 0, out + base*256, 256, 0, 2);
  }
}

// Round 17
// 2642.017 us; speedup vs baseline: 1.0351x; 1.0351x over previous
//
#include <hip/hip_runtime.h>

typedef __attribute__((ext_vector_type(8))) short short8;
typedef __attribute__((ext_vector_type(4))) float f32x4;

#define MFMA16 __builtin_amdgcn_mfma_f32_16x16x32_bf16

__device__ __forceinline__ unsigned short f2bf(float f){
  union { float f; unsigned int u; } v; v.f = f;
  unsigned int u = v.u + 0x7fffu + ((v.u >> 16) & 1u);  // RNE
  return (unsigned short)(u >> 16);
}
__device__ __forceinline__ float lo2f(unsigned int u){ union { unsigned int u; float f; } v; v.u = u << 16; return v.f; }
__device__ __forceinline__ float hi2f(unsigned int u){ union { unsigned int u; float f; } v; v.u = u & 0xffff0000u; return v.f; }

// async global->LDS, 16B per lane (dest = base + lane*16, HW-defined)
__device__ __forceinline__ void load_lds16(const unsigned short* g, unsigned short* l){
  typedef const __attribute__((address_space(1))) unsigned int* gp_t;
  typedef __attribute__((address_space(3))) unsigned int* sp_t;
  __builtin_amdgcn_global_load_lds((gp_t)(const void*)g, (sp_t)(void*)l, 16, 0, 0);
}

// ---------------- ws layout (weights, elems) ----------------
constexpr size_t W1T_OFF  = 0;                               // 8 x [256][512]
constexpr size_t W1T_HSTR = 512*256;
constexpr size_t W2T_OFF  = W1T_OFF + 8*W1T_HSTR;            // 8 x [256][256]
constexpr size_t W2T_HSTR = 256*256;
constexpr size_t OQKV_OFF = W2T_OFF + 8*W2T_HSTR;            // [768][2048]
constexpr size_t OW1_OFF  = OQKV_OFF + (size_t)768*2048;     // [256][2304]
constexpr size_t OW2_OFF  = OW1_OFF + (size_t)256*2304;      // [256][256]
constexpr size_t WQC_OFF  = OW2_OFF + (size_t)256*256;       // 8 x [256][256] bf16 cast
constexpr size_t WKC_OFF  = WQC_OFF + (size_t)8*65536;
constexpr size_t WVC_OFF  = WKC_OFF + (size_t)8*65536;
constexpr size_t MT_OFF   = WVC_OFF + (size_t)8*65536;       // 8 x [256][256]: MT[m][i] = sum_j Wk[m][j]Wq[i][j]
constexpr size_t PT_OFF   = MT_OFF + (size_t)8*65536;        // 8 x [256][256]: PT[j][m] = sum_d Wv[m][d]W1a[d][j]
constexpr size_t WT_ELEMS = PT_OFF + (size_t)8*65536;
constexpr size_t XP_OFFB  = (WT_ELEMS*2 + 255) & ~(size_t)255;
constexpr size_t XP_BYTES = (size_t)131072*256*2;            // xp: row-major [BT][256]
constexpr size_t FEATS_OFFB = XP_OFFB + XP_BYTES;

constexpr int LDX  = 264;   // xs tile stride (528B -> bank step 4)
constexpr int LDQ  = 520;   // qs tile stride (1040B -> bank step 4)

// ---------------- prep: transpose weights to bf16 [N][K] ----------------
__global__ void k_transpose(const float* __restrict__ src, unsigned short* __restrict__ dst,
                            int K, int N, long long srcStride, long long dstStride){
  const int i = blockIdx.x*256 + threadIdx.x;
  const int b = blockIdx.y;
  const int n = i / K, k = i - n*K;
  dst[(size_t)b*dstStride + i] = f2bf(src[(size_t)b*srcStride + (size_t)k*N + n]);
}

// ---------------- prep: plain bf16 cast (keeps orientation) ----------------
__global__ void k_cast(const float* __restrict__ src, unsigned short* __restrict__ dst){
  const size_t i = ((size_t)blockIdx.x*256 + threadIdx.x) * 4;
  float4 a = *(const float4*)(src + i);
  dst[i+0] = f2bf(a.x); dst[i+1] = f2bf(a.y); dst[i+2] = f2bf(a.z); dst[i+3] = f2bf(a.w);
}

// ---------------- xp = bf16(x + pos), row-major ----------------
__global__ void k_xp(const float* __restrict__ x, const float* __restrict__ pos,
                     unsigned short* __restrict__ xp){
  const size_t i = ((size_t)blockIdx.x*256 + threadIdx.x) * 8;
  const int colb = (int)(i & 255);
  const int t = (int)((i >> 8) & 7);
  float4 a0 = *(const float4*)(x + i);
  float4 a1 = *(const float4*)(x + i + 4);
  float4 p0 = *(const float4*)(pos + t*256 + colb);
  float4 p1 = *(const float4*)(pos + t*256 + colb + 4);
  short8 o;
  o[0]=(short)f2bf(a0.x+p0.x); o[1]=(short)f2bf(a0.y+p0.y);
  o[2]=(short)f2bf(a0.z+p0.z); o[3]=(short)f2bf(a0.w+p0.w);
  o[4]=(short)f2bf(a1.x+p1.x); o[5]=(short)f2bf(a1.y+p1.y);
  o[6]=(short)f2bf(a1.z+p1.z); o[7]=(short)f2bf(a1.w+p1.w);
  *(short8*)(xp + i) = o;
}

// ==================== per-head fused kernel (r14 config + B-reg-prefetch) ====================
// grid (R/64, 8 heads), 512 threads = 8 waves, 1 block/CU (proven best).
// All B fragments of a GEMM phase are loaded into registers BEFORE the MFMA
// loop so their ~200cy L2 latency is paid once per phase, not per iteration.
__global__ __launch_bounds__(512, 2) void k_head(
    const unsigned short* __restrict__ xp,
    const unsigned short* __restrict__ WT,
    const float* __restrict__ hb1, const float* __restrict__ hb2,
    unsigned short* __restrict__ feats)
{
  __shared__ __align__(16) unsigned short xs[64*LDX];
  __shared__ __align__(16) unsigned short qs[64*LDQ];   // cols 0-255: G -> h1 ; cols 256-511: axp

  const int h    = blockIdx.y;
  const int r0   = blockIdx.x << 6;
  const int tid  = threadIdx.x;
  const int wave = tid >> 6;
  const int lane = tid & 63;
  const int l16  = lane & 15;
  const int lq   = lane >> 4;

  // load xp tile (64 x 256)
  {
    const int row = tid >> 3, c0 = (tid & 7) << 5;
    const short8* s = (const short8*)(xp + (size_t)(r0 + row)*256 + c0);
    short8* d = (short8*)(xs + row*LDX + c0);
    #pragma unroll
    for (int j = 0; j < 4; j++) d[j] = s[j];
  }
  __syncthreads();

  // P1: G = xp @ MT^T  [64,256]@[256,256]; wave owns 32 cols; B prefetched
  {
    const unsigned short* Bm = WT + MT_OFF + (size_t)h*65536;
    short8 bb[16];
    #pragma unroll
    for (int kk = 0; kk < 8; kk++){
      const int ko = (kk << 5) + (lq << 3);
      #pragma unroll
      for (int n = 0; n < 2; n++){
        const int col = (wave << 5) + (n << 4) + l16;
        bb[kk*2 + n] = *(const short8*)(Bm + (size_t)col*256 + ko);
      }
    }
    f32x4 acc[4][2];
    #pragma unroll
    for (int m = 0; m < 4; m++){ acc[m][0] = (f32x4){0.f,0.f,0.f,0.f}; acc[m][1] = (f32x4){0.f,0.f,0.f,0.f}; }
    #pragma unroll
    for (int kk = 0; kk < 8; kk++){
      const int ko = (kk << 5) + (lq << 3);
      short8 a[4];
      #pragma unroll
      for (int m = 0; m < 4; m++)
        a[m] = *(const short8*)(xs + (m*16 + l16)*LDX + ko);
      #pragma unroll
      for (int n = 0; n < 2; n++)
        #pragma unroll
        for (int m = 0; m < 4; m++)
          acc[m][n] = MFMA16(a[m], bb[kk*2 + n], acc[m][n], 0, 0, 0);
    }
    #pragma unroll
    for (int n = 0; n < 2; n++){
      const int col = (wave << 5) + (n << 4) + l16;
      #pragma unroll
      for (int m = 0; m < 4; m++)
        #pragma unroll
        for (int r = 0; r < 4; r++)
          qs[(m*16 + lq*4 + r)*LDQ + col] = f2bf(acc[m][n][r]);
    }
  }
  __syncthreads();

  // P2+P3 fused: scores + softmax (lane=(t,s)) then axp via shfl-broadcast P
  {
    const int t = lane >> 3, s = lane & 7;
    const unsigned short* Qr = qs + (wave*8 + t)*LDQ;        // G row
    const unsigned short* Kr = xs + (wave*8 + s)*LDX;        // xp row
    float e0 = 0.f, e1 = 0.f, e2 = 0.f, e3 = 0.f;
    #pragma unroll
    for (int c = 0; c < 256; c += 8){
      union { short8 v; unsigned int u[4]; } qa, kb;
      qa.v = *(const short8*)(Qr + c);
      kb.v = *(const short8*)(Kr + c);
      e0 = fmaf(lo2f(qa.u[0]), lo2f(kb.u[0]), e0);
      e1 = fmaf(hi2f(qa.u[0]), hi2f(kb.u[0]), e1);
      e2 = fmaf(lo2f(qa.u[1]), lo2f(kb.u[1]), e2);
      e3 = fmaf(hi2f(qa.u[1]), hi2f(kb.u[1]), e3);
      e0 = fmaf(lo2f(qa.u[2]), lo2f(kb.u[2]), e0);
      e1 = fmaf(hi2f(qa.u[2]), hi2f(kb.u[2]), e1);
      e2 = fmaf(lo2f(qa.u[3]), lo2f(kb.u[3]), e2);
      e3 = fmaf(hi2f(qa.u[3]), hi2f(kb.u[3]), e3);
    }
    float e = (e0 + e1) + (e2 + e3);
    e *= 0.0625f;                    // 1/sqrt(256)
    if (s > t) e = -1e30f;           // causal
    float mx = fmaxf(e, __shfl_xor(e, 1));
    mx = fmaxf(mx, __shfl_xor(mx, 2));
    mx = fmaxf(mx, __shfl_xor(mx, 4));
    float p = (s <= t) ? __expf(e - mx) : 0.f;
    float sum = p;
    sum += __shfl_xor(sum, 1);
    sum += __shfl_xor(sum, 2);
    sum += __shfl_xor(sum, 4);
    const float pn = p / sum;        // lane (t,s) holds P[t][s]

    // axp = attn @ xp -> qs cols 256-511 ; lane roles (t, c8) reuse t, c8=s
    const int c8 = s;
    float o[32];
    #pragma unroll
    for (int j = 0; j < 32; j++) o[j] = 0.f;
    #pragma unroll
    for (int ss = 0; ss < 8; ss++){
      const float w = __shfl(pn, (lane & 56) + ss);
      const unsigned short* Vr = xs + (wave*8 + ss)*LDX + (c8 << 5);
      #pragma unroll
      for (int jj = 0; jj < 4; jj++){
        union { short8 v; unsigned int u[4]; } vv;
        vv.v = *(const short8*)(Vr + jj*8);
        #pragma unroll
        for (int q = 0; q < 4; q++){
          o[jj*8 + 2*q]     = fmaf(w, lo2f(vv.u[q]), o[jj*8 + 2*q]);
          o[jj*8 + 2*q + 1] = fmaf(w, hi2f(vv.u[q]), o[jj*8 + 2*q + 1]);
        }
      }
    }
    unsigned short* Or = qs + (wave*8 + t)*LDQ + 256 + (c8 << 5);
    #pragma unroll
    for (int j = 0; j < 32; j++) Or[j] = f2bf(o[j]);
  }
  __syncthreads();

  // P4: h1 = relu([axp | xp] @ [PT | W1b]^T + b1) -> qs cols 0-255; B prefetched (2 banks)
  {
    const unsigned short* Bp = WT + PT_OFF + (size_t)h*65536;       // [256][256], k<256
    const unsigned short* B1 = WT + W1T_OFF + (size_t)h*W1T_HSTR;   // [256][512], k in [256,512)
    short8 bb1[16], bb2[16];
    #pragma unroll
    for (int kk = 0; kk < 8; kk++){
      const int ko = (kk << 5) + (lq << 3);
      #pragma unroll
      for (int n = 0; n < 2; n++){
        const int col = (wave << 5) + (n << 4) + l16;
        bb1[kk*2 + n] = *(const short8*)(Bp + (size_t)col*256 + ko);
        bb2[kk*2 + n] = *(const short8*)(B1 + (size_t)col*512 + 256 + ko);   // W1b half: k in [256,512)
      }
    }
    f32x4 acc[4][2];
    #pragma unroll
    for (int m = 0; m < 4; m++){ acc[m][0] = (f32x4){0.f,0.f,0.f,0.f}; acc[m][1] = (f32x4){0.f,0.f,0.f,0.f}; }
    #pragma unroll
    for (int kk = 0; kk < 8; kk++){           // k<256: A = axp (qs cols 256-511)
      const int ko = (kk << 5) + (lq << 3);
      short8 a[4];
      #pragma unroll
      for (int m = 0; m < 4; m++)
        a[m] = *(const short8*)(qs + (m*16 + l16)*LDQ + 256 + ko);
      #pragma unroll
      for (int n = 0; n < 2; n++)
        #pragma unroll
        for (int m = 0; m < 4; m++)
          acc[m][n] = MFMA16(a[m], bb1[kk*2 + n], acc[m][n], 0, 0, 0);
    }
    #pragma unroll
    for (int kk = 0; kk < 8; kk++){           // k in [256,512): A = xp (xs)
      const int ko = (kk << 5) + (lq << 3);
      short8 a[4];
      #pragma unroll
      for (int m = 0; m < 4; m++)
        a[m] = *(const short8*)(xs + (m*16 + l16)*LDX + ko);
      #pragma unroll
      for (int n = 0; n < 2; n++)
        #pragma unroll
        for (int m = 0; m < 4; m++)
          acc[m][n] = MFMA16(a[m], bb2[kk*2 + n], acc[m][n], 0, 0, 0);
    }
    #pragma unroll
    for (int n = 0; n < 2; n++){
      const int col = (wave << 5) + (n << 4) + l16;
      const float bv = hb1[(h << 8) + col];
      #pragma unroll
      for (int m = 0; m < 4; m++)
        #pragma unroll
        for (int r = 0; r < 4; r++)
          qs[(m*16 + lq*4 + r)*LDQ + col] = f2bf(fmaxf(acc[m][n][r] + bv, 0.f));
    }
  }
  __syncthreads();

  // P5: feats_h = h1 @ W2T^T + b2; B prefetched
  {
    const unsigned short* W = WT + W2T_OFF + (size_t)h * W2T_HSTR;
    short8 bb[16];
    #pragma unroll
    for (int kk = 0; kk < 8; kk++){
      const int ko = (kk << 5) + (lq << 3);
      #pragma unroll
      for (int n = 0; n < 2; n++){
        const int col = (wave << 5) + (n << 4) + l16;
        bb[kk*2 + n] = *(const short8*)(W + (size_t)col*256 + ko);
      }
    }
    f32x4 acc[4][2];
    #pragma unroll
    for (int m = 0; m < 4; m++){ acc[m][0] = (f32x4){0.f,0.f,0.f,0.f}; acc[m][1] = (f32x4){0.f,0.f,0.f,0.f}; }
    #pragma unroll
    for (int kk = 0; kk < 8; kk++){
      const int ko = (kk << 5) + (lq << 3);
      short8 a[4];
      #pragma unroll
      for (int m = 0; m < 4; m++)
        a[m] = *(const short8*)(qs + (m*16 + l16)*LDQ + ko);
      #pragma unroll
      for (int n = 0; n < 2; n++)
        #pragma unroll
        for (int m = 0; m < 4; m++)
          acc[m][n] = MFMA16(a[m], bb[kk*2 + n], acc[m][n], 0, 0, 0);
    }
    #pragma unroll
    for (int n = 0; n < 2; n++){
      const int col = (wave << 5) + (n << 4) + l16;
      const float bv = hb2[(h << 8) + col];
      #pragma unroll
      for (int m = 0; m < 4; m++)
        #pragma unroll
        for (int r = 0; r < 4; r++)
          feats[(size_t)(r0 + m*16 + lq*4 + r)*2048 + (h << 8) + col] = f2bf(acc[m][n][r] + bv);
    }
  }
}

// ==================== output-layer attention ====================
__global__ __launch_bounds__(512, 4) void k_attn2(
    const unsigned short* __restrict__ qkv2, unsigned short* __restrict__ ao)
{
  __shared__ float aw[8][64];
  const int r0   = blockIdx.x * 64;
  const int tid  = threadIdx.x;
  const int wave = tid >> 6;
  const int lane = tid & 63;
  const int g = wave;
  {
    const int t = lane >> 3, s = lane & 7;
    const unsigned short* Qr = qkv2 + (size_t)(r0 + g*8 + t)*768;
    const unsigned short* Kr = qkv2 + (size_t)(r0 + g*8 + s)*768 + 256;
    float e0 = 0.f, e1 = 0.f, e2 = 0.f, e3 = 0.f;
    #pragma unroll
    for (int c = 0; c < 256; c += 8){
      union { short8 v; unsigned int u[4]; } qa, kb;
      qa.v = *(const short8*)(Qr + c);
      kb.v = *(const short8*)(Kr + c);
      e0 = fmaf(lo2f(qa.u[0]), lo2f(kb.u[0]), e0);
      e1 = fmaf(hi2f(qa.u[0]), hi2f(kb.u[0]), e1);
      e2 = fmaf(lo2f(qa.u[1]), lo2f(kb.u[1]), e2);
      e3 = fmaf(hi2f(qa.u[1]), hi2f(kb.u[1]), e3);
      e0 = fmaf(lo2f(qa.u[2]), lo2f(kb.u[2]), e0);
      e1 = fmaf(hi2f(qa.u[2]), hi2f(kb.u[2]), e1);
      e2 = fmaf(lo2f(qa.u[3]), lo2f(kb.u[3]), e2);
      e3 = fmaf(hi2f(qa.u[3]), hi2f(kb.u[3]), e3);
    }
    float e = (e0 + e1) + (e2 + e3);
    e *= 0.0625f;
    if (s > t) e = -1e30f;
    float mx = fmaxf(e, __shfl_xor(e, 1));
    mx = fmaxf(mx, __shfl_xor(mx, 2));
    mx = fmaxf(mx, __shfl_xor(mx, 4));
    float p = (s <= t) ? __expf(e - mx) : 0.f;
    float sum = p;
    sum += __shfl_xor(sum, 1);
    sum += __shfl_xor(sum, 2);
    sum += __shfl_xor(sum, 4);
    aw[g][lane] = p / sum;
  }
  __syncthreads();
  {
    const int t = lane >> 3, c8 = lane & 7;
    float o[32];
    #pragma unroll
    for (int j = 0; j < 32; j++) o[j] = 0.f;
    #pragma unroll
    for (int s = 0; s < 8; s++){
      const float w = aw[g][t*8 + s];
      const unsigned short* Vr = qkv2 + (size_t)(r0 + g*8 + s)*768 + 512 + (c8 << 5);
      #pragma unroll
      for (int jj = 0; jj < 4; jj++){
        union { short8 v; unsigned int u[4]; } vv;
        vv.v = *(const short8*)(Vr + jj*8);
        #pragma unroll
        for (int q = 0; q < 4; q++){
          o[jj*8 + 2*q]     = fmaf(w, lo2f(vv.u[q]), o[jj*8 + 2*q]);
          o[jj*8 + 2*q + 1] = fmaf(w, hi2f(vv.u[q]), o[jj*8 + 2*q + 1]);
        }
      }
    }
    unsigned short* Or = ao + (size_t)(r0 + g*8 + t)*256 + (c8 << 5);
    #pragma unroll
    for (int jj = 0; jj < 4; jj++){
      short8 v;
      #pragma unroll
      for (int q = 0; q < 8; q++) v[q] = (short)f2bf(o[jj*8 + q]);
      *(short8*)(Or + jj*8) = v;
    }
  }
}

// ==================== grouped tiled GEMM with global_load_lds staging ====================
// C_h[M,N] = A_h @ B_h^T. blockIdx.y = h*tilesN + ntile. 128x128 tile, 4 waves,
// BK=64, double-buffered LDS via async global->LDS (linear dest, swizzled source,
// XOR-swizzled frag reads). EPI: 0 = bf16; 1 = bias+relu bf16; 2 = bias f32.
template<int EPI>
__global__ __launch_bounds__(256, 2) void k_gemmg(
    const unsigned short* __restrict__ A1, long long lda1, int K1, long long a1hstr,
    const unsigned short* __restrict__ A2, long long lda2,
    const unsigned short* __restrict__ B, long long ldb, int K, long long bhstr,
    const float* __restrict__ bias, long long biashstr,
    void* __restrict__ Cv, long long ldc, long long chstr,
    int tilesN)
{
  __shared__ __align__(16) unsigned short SM[36864];   // A dbuf 32KB | B dbuf 32KB | (epilogue reuse)
  unsigned short* As = SM;            // [2][8192] elems, linear [128][64] per buf
  unsigned short* Bs = SM + 16384;    // [2][8192]

  const int h  = blockIdx.y / tilesN;
  const int c0 = (blockIdx.y - h*tilesN) * 128;
  A1 += (size_t)h * a1hstr;
  B  += (size_t)h * bhstr;

  const int tid  = threadIdx.x;
  const int wave = tid >> 6, lane = tid & 63;
  const int l16  = lane & 15, lq = lane >> 4;
  const int wm   = wave >> 1, wn = wave & 1;
  const size_t r0 = (size_t)blockIdx.x * 128;

  const int lrow = lane >> 3;                      // 0..7
  const int lcol = ((lane & 7) ^ lrow) << 3;       // swizzled source col (elems)
  const int axor = (l16 & 7) << 3;                 // frag-read XOR (elems)

  f32x4 acc[4][4];
  #pragma unroll
  for (int m = 0; m < 4; m++)
    #pragma unroll
    for (int n = 0; n < 4; n++) acc[m][n] = (f32x4){0.f,0.f,0.f,0.f};

  const int KS = K >> 6;

  // stage one 128x64 A-tile + B-tile into buf (16 x 1KB wave-calls each)
  auto stage = [&](int buf, int k0){
    #pragma unroll
    for (int jj = 0; jj < 4; jj++){
      const int c = wave*4 + jj;                   // chunk 0..15 (8 rows each)
      const int row = c*8 + lrow;
      const unsigned short* ga;
      if (k0 < K1) ga = A1 + (r0 + row)*lda1 + k0 + lcol;
      else         ga = A2 + (r0 + row)*lda2 + (k0 - K1) + lcol;
      load_lds16(ga, As + buf*8192 + c*512);
      const unsigned short* gb = B + (size_t)(c0 + row)*ldb + k0 + lcol;
      load_lds16(gb, Bs + buf*8192 + c*512);
    }
  };

  stage(0, 0);
  __syncthreads();   // drains vmcnt

  int cur = 0;
  for (int s2 = 0; s2 < KS; s2++){
    if (s2 + 1 < KS) stage(cur^1, (s2 + 1) << 6);  // async, in flight under MFMAs
    const unsigned short* Ab = As + cur*8192;
    const unsigned short* Bb = Bs + cur*8192;
    #pragma unroll
    for (int kk = 0; kk < 2; kk++){
      const int cb = (kk << 5) + (lq << 3);
      short8 af[4], bf[4];
      #pragma unroll
      for (int m = 0; m < 4; m++)
        af[m] = *(const short8*)(Ab + (wm*64 + m*16 + l16)*64 + (cb ^ axor));
      #pragma unroll
      for (int n = 0; n < 4; n++)
        bf[n] = *(const short8*)(Bb + (wn*64 + n*16 + l16)*64 + (cb ^ axor));
      #pragma unroll
      for (int n = 0; n < 4; n++)
        #pragma unroll
        for (int m = 0; m < 4; m++)
          acc[m][n] = MFMA16(af[m], bf[n], acc[m][n], 0,0,0);
    }
    __syncthreads();   // drains prefetch + guards buf swap
    cur ^= 1;
  }

  // epilogue: stage C in LDS, coalesced write
  if (EPI == 2){
    float* Cs = (float*)SM;           // [128][130] f32
    float* C = (float*)Cv + (size_t)h * chstr;
    #pragma unroll
    for (int n = 0; n < 4; n++){
      const int col = wn*64 + n*16 + l16;
      const float bv = bias[(size_t)h*biashstr + c0 + col];
      #pragma unroll
      for (int m = 0; m < 4; m++)
        #pragma unroll
        for (int r = 0; r < 4; r++)
          Cs[(wm*64 + m*16 + lq*4 + r)*130 + col] = acc[m][n][r] + bv;
    }
    __syncthreads();
    #pragma unroll
    for (int it = 0; it < 16; it++){
      const int idx = it*256 + tid;
      const int row = idx >> 5, c4 = (idx & 31) << 2;
      *(float4*)(C + (r0 + row)*ldc + c0 + c4) = *(const float4*)(Cs + row*130 + c4);
    }
  } else {
    unsigned short* Cs = SM;          // [128][132] bf16
    unsigned short* C = (unsigned short*)Cv + (size_t)h * chstr;
    #pragma unroll
    for (int n = 0; n < 4; n++){
      const int col = wn*64 + n*16 + l16;
      const float bv = (EPI == 1) ? bias[(size_t)h*biashstr + c0 + col] : 0.f;
      #pragma unroll
      for (int m = 0; m < 4; m++)
        #pragma unroll
        for (int r = 0; r < 4; r++){
          float v = acc[m][n][r] + bv;
          if (EPI == 1) v = fmaxf(v, 0.f);
          Cs[(wm*64 + m*16 + lq*4 + r)*132 + col] = f2bf(v);
        }
    }
    __syncthreads();
    #pragma unroll
    for (int it = 0; it < 8; it++){
      const int idx = it*256 + tid;
      const int row = idx >> 4, c8 = (idx & 15) << 3;
      *(short8*)(C + (r0 + row)*ldc + c0 + c8) = *(const short8*)(Cs + row*132 + c8);
    }
  }
}

extern "C" void kernel_launch(void* const* d_in, const int* in_sizes, int n_in,
                              void* d_out, int out_size, void* d_ws, size_t ws_size,
                              hipStream_t stream) {
  (void)n_in; (void)out_size;
  const float* x    = (const float*)d_in[0];
  const float* pos  = (const float*)d_in[1];
  const float* hWq  = (const float*)d_in[2];
  const float* hWk  = (const float*)d_in[3];
  const float* hWv  = (const float*)d_in[4];
  const float* hW1  = (const float*)d_in[5];
  const float* hb1  = (const float*)d_in[6];
  const float* hW2  = (const float*)d_in[7];
  const float* hb2  = (const float*)d_in[8];
  const float* oWq  = (const float*)d_in[9];
  const float* oWk  = (const float*)d_in[10];
  const float* oWv  = (const float*)d_in[11];
  const float* oW1  = (const float*)d_in[12];
  const float* ob1  = (const float*)d_in[13];
  const float* oW2  = (const float*)d_in[14];
  const float* ob2  = (const float*)d_in[15];

  unsigned short* WT  = (unsigned short*)d_ws;
  unsigned short* xp  = (unsigned short*)((char*)d_ws + XP_OFFB);
  float* out = (float*)d_out;

  const long long BT = in_sizes[0] / 256;   // 131072

  // chunk sizing: feats + qkv2 + ao + h1 rings = R*6656 bytes; keep L3-resident
  const size_t capB = (ws_size > FEATS_OFFB) ? (ws_size - FEATS_OFFB) : 0;
  long long R = (long long)(capB / 6656);
  if (R > 16384) R = 16384;
  if (R > BT) R = BT;
  R &= ~127LL;
  if (R < 128) R = 128;

  unsigned short* feats = (unsigned short*)((char*)d_ws + FEATS_OFFB);
  unsigned short* qkv2  = (unsigned short*)((char*)feats + (size_t)R*4096);
  unsigned short* ao    = (unsigned short*)((char*)qkv2  + (size_t)R*1536);
  unsigned short* h1o   = (unsigned short*)((char*)ao    + (size_t)R*512);

  // ---- prep: transposes, casts, weight-product GEMMs ----
  k_transpose<<<dim3(512,8),  256, 0, stream>>>(hW1, WT + W1T_OFF,            512, 256, 131072, 131072);
  k_transpose<<<dim3(256,8),  256, 0, stream>>>(hW2, WT + W2T_OFF,            256, 256, 65536, 65536);
  k_transpose<<<dim3(2048,1), 256, 0, stream>>>(oWq, WT + OQKV_OFF,           2048, 256, 0, 0);
  k_transpose<<<dim3(2048,1), 256, 0, stream>>>(oWk, WT + OQKV_OFF + 524288,  2048, 256, 0, 0);
  k_transpose<<<dim3(2048,1), 256, 0, stream>>>(oWv, WT + OQKV_OFF + 1048576, 2048, 256, 0, 0);
  k_transpose<<<dim3(2304,1), 256, 0, stream>>>(oW1, WT + OW1_OFF,            2304, 256, 0, 0);
  k_transpose<<<dim3(256,1),  256, 0, stream>>>(oW2, WT + OW2_OFF,            256, 256, 0, 0);
  k_cast<<<512, 256, 0, stream>>>(hWq, WT + WQC_OFF);
  k_cast<<<512, 256, 0, stream>>>(hWk, WT + WKC_OFF);
  k_cast<<<512, 256, 0, stream>>>(hWv, WT + WVC_OFF);

  // MT_h[m][i] = sum_j Wk[m][j] Wq[i][j]
  k_gemmg<0><<<dim3(2, 16), 256, 0, stream>>>(
      WT + WKC_OFF, 256, 1<<30, 65536, WT + WKC_OFF, 256,
      WT + WQC_OFF, 256, 256, 65536, nullptr, 0,
      WT + MT_OFF, 256, 65536, 2);

  // PT_h[j][m] = sum_d W1a[d][j] Wv[m][d]
  k_gemmg<0><<<dim3(2, 16), 256, 0, stream>>>(
      WT + W1T_OFF, 512, 1<<30, W1T_HSTR, WT + W1T_OFF, 512,
      WT + WVC_OFF, 256, 256, 65536, nullptr, 0,
      WT + PT_OFF, 256, 65536, 2);

  k_xp<<<(int)(BT/8), 256, 0, stream>>>(x, pos, xp);

  for (long long base = 0; base < BT; base += R) {
    const long long Rc = (BT - base < R) ? (BT - base) : R;
    const int mt64  = (int)(Rc / 64);
    const int mt128 = (int)(Rc / 128);

    k_head<<<dim3(mt64, 8), 512, 0, stream>>>(xp + base*256, WT, hb1, hb2, feats);

    // QKV2: A = feats [R][2048], K=2048
    k_gemmg<0><<<dim3(mt128, 6), 256, 0, stream>>>(
        feats, 2048, 1<<30, 0, feats, 2048,
        WT + OQKV_OFF, 2048, 2048, 0, nullptr, 0, qkv2, 768, 0, 6);

    k_attn2<<<mt64, 512, 0, stream>>>(qkv2, ao);

    // FFN1o: A = [ao | feats], K=2304
    k_gemmg<1><<<dim3(mt128, 2), 256, 0, stream>>>(
        ao, 256, 256, 0, feats, 2048,
        WT + OW1_OFF, 2304, 2304, 0, ob1, 0, h1o, 256, 0, 2);

    // FFN2o: A = h1o, K=256
    k_gemmg<2><<<dim3(mt128, 2), 256, 0, stream>>>(
        h1o, 256, 1<<30, 0, h1o, 256,
        WT + OW2_OFF, 256, 256, 0, ob2, 0, out + base*256, 256, 0, 2);
  }
}

// Round 18
// 2100.310 us; speedup vs baseline: 1.3021x; 1.2579x over previous
//
#include <hip/hip_runtime.h>

typedef __attribute__((ext_vector_type(8))) short short8;
typedef __attribute__((ext_vector_type(4))) float f32x4;

#define MFMA16 __builtin_amdgcn_mfma_f32_16x16x32_bf16

__device__ __forceinline__ unsigned short f2bf(float f){
  union { float f; unsigned int u; } v; v.f = f;
  unsigned int u = v.u + 0x7fffu + ((v.u >> 16) & 1u);  // RNE
  return (unsigned short)(u >> 16);
}
__device__ __forceinline__ float lo2f(unsigned int u){ union { unsigned int u; float f; } v; v.u = u << 16; return v.f; }
__device__ __forceinline__ float hi2f(unsigned int u){ union { unsigned int u; float f; } v; v.u = u & 0xffff0000u; return v.f; }

// async global->LDS, 16B per lane (dest = base + lane*16, HW-defined)
__device__ __forceinline__ void load_lds16(const unsigned short* g, unsigned short* l){
  typedef const __attribute__((address_space(1))) unsigned int* gp_t;
  typedef __attribute__((address_space(3))) unsigned int* sp_t;
  __builtin_amdgcn_global_load_lds((gp_t)(const void*)g, (sp_t)(void*)l, 16, 0, 0);
}

// ---------------- ws layout (weights, elems) ----------------
constexpr size_t W1T_OFF  = 0;                               // 8 x [256][512]
constexpr size_t W1T_HSTR = 512*256;
constexpr size_t W2T_OFF  = W1T_OFF + 8*W1T_HSTR;            // 8 x [256][256]
constexpr size_t W2T_HSTR = 256*256;
constexpr size_t OQKV_OFF = W2T_OFF + 8*W2T_HSTR;            // [768][2048]
constexpr size_t OW1_OFF  = OQKV_OFF + (size_t)768*2048;     // [256][2304]
constexpr size_t OW2_OFF  = OW1_OFF + (size_t)256*2304;      // [256][256]
constexpr size_t WQC_OFF  = OW2_OFF + (size_t)256*256;       // 8 x [256][256] bf16 cast
constexpr size_t WKC_OFF  = WQC_OFF + (size_t)8*65536;
constexpr size_t WVC_OFF  = WKC_OFF + (size_t)8*65536;
constexpr size_t MT_OFF   = WVC_OFF + (size_t)8*65536;       // 8 x [256][256]: MT[m][i] = sum_j Wk[m][j]Wq[i][j]
constexpr size_t PT_OFF   = MT_OFF + (size_t)8*65536;        // 8 x [256][256]: PT[j][m] = sum_d Wv[m][d]W1a[d][j]
constexpr size_t WT_ELEMS = PT_OFF + (size_t)8*65536;
constexpr size_t XP_OFFB  = (WT_ELEMS*2 + 255) & ~(size_t)255;
constexpr size_t XP_BYTES = (size_t)131072*256*2;            // xp: row-major [BT][256]
constexpr size_t FEATS_OFFB = XP_OFFB + XP_BYTES;

constexpr int LDX  = 264;   // tile stride (528B -> bank step 4, benign 2-way)

// ---------------- prep: transpose weights to bf16 [N][K] ----------------
__global__ void k_transpose(const float* __restrict__ src, unsigned short* __restrict__ dst,
                            int K, int N, long long srcStride, long long dstStride){
  const int i = blockIdx.x*256 + threadIdx.x;
  const int b = blockIdx.y;
  const int n = i / K, k = i - n*K;
  dst[(size_t)b*dstStride + i] = f2bf(src[(size_t)b*srcStride + (size_t)k*N + n]);
}

// ---------------- prep: plain bf16 cast (keeps orientation) ----------------
__global__ void k_cast(const float* __restrict__ src, unsigned short* __restrict__ dst){
  const size_t i = ((size_t)blockIdx.x*256 + threadIdx.x) * 4;
  float4 a = *(const float4*)(src + i);
  dst[i+0] = f2bf(a.x); dst[i+1] = f2bf(a.y); dst[i+2] = f2bf(a.z); dst[i+3] = f2bf(a.w);
}

// ---------------- xp = bf16(x + pos), row-major ----------------
__global__ void k_xp(const float* __restrict__ x, const float* __restrict__ pos,
                     unsigned short* __restrict__ xp){
  const size_t i = ((size_t)blockIdx.x*256 + threadIdx.x) * 8;
  const int colb = (int)(i & 255);
  const int t = (int)((i >> 8) & 7);
  float4 a0 = *(const float4*)(x + i);
  float4 a1 = *(const float4*)(x + i + 4);
  float4 p0 = *(const float4*)(pos + t*256 + colb);
  float4 p1 = *(const float4*)(pos + t*256 + colb + 4);
  short8 o;
  o[0]=(short)f2bf(a0.x+p0.x); o[1]=(short)f2bf(a0.y+p0.y);
  o[2]=(short)f2bf(a0.z+p0.z); o[3]=(short)f2bf(a0.w+p0.w);
  o[4]=(short)f2bf(a1.x+p1.x); o[5]=(short)f2bf(a1.y+p1.y);
  o[6]=(short)f2bf(a1.z+p1.z); o[7]=(short)f2bf(a1.w+p1.w);
  *(short8*)(xp + i) = o;
}

// ==================== per-head fused kernel — TWO 64-row tiles per block ====================
// grid (R/128, 8 heads), 512 threads = 8 waves, 1 block/CU (132KB LDS).
// Both tiles share each B fragment in a register (2 MFMAs per b load):
// halves L2 B-traffic and barrier count per row; two independent chains
// between barriers give the scheduler overlap. Phase bodies = r15-proven.
__global__ __launch_bounds__(512, 2) void k_head(
    const unsigned short* __restrict__ xp,
    const unsigned short* __restrict__ WT,
    const float* __restrict__ hb1, const float* __restrict__ hb2,
    unsigned short* __restrict__ feats)
{
  __shared__ __align__(16) unsigned short xsA[64*LDX];  // xpA -> h1A
  __shared__ __align__(16) unsigned short xsB[64*LDX];  // xpB -> h1B
  __shared__ __align__(16) unsigned short qsA[64*LDX];  // G_A -> axp_A (in place)
  __shared__ __align__(16) unsigned short qsB[64*LDX];  // G_B -> axp_B

  const int h    = blockIdx.y;
  const int r0   = blockIdx.x << 7;       // 128 rows: A = r0..r0+63, B = r0+64..r0+127
  const int tid  = threadIdx.x;
  const int wave = tid >> 6;
  const int lane = tid & 63;
  const int l16  = lane & 15;
  const int lq   = lane >> 4;

  // load both xp tiles (64 x 256 each)
  {
    const int row = tid >> 3, c0 = (tid & 7) << 5;
    const short8* sA = (const short8*)(xp + (size_t)(r0 + row)*256 + c0);
    const short8* sB = (const short8*)(xp + (size_t)(r0 + 64 + row)*256 + c0);
    short8* dA = (short8*)(xsA + row*LDX + c0);
    short8* dB = (short8*)(xsB + row*LDX + c0);
    #pragma unroll
    for (int j = 0; j < 4; j++){ dA[j] = sA[j]; dB[j] = sB[j]; }
  }
  __syncthreads();

  // P1: G = xp @ MT^T for both tiles; each b fragment used twice
  {
    const unsigned short* Bm = WT + MT_OFF + (size_t)h*65536;
    f32x4 accA[4][2], accB[4][2];
    #pragma unroll
    for (int m = 0; m < 4; m++)
      #pragma unroll
      for (int n = 0; n < 2; n++){ accA[m][n] = (f32x4){0.f,0.f,0.f,0.f}; accB[m][n] = (f32x4){0.f,0.f,0.f,0.f}; }
    #pragma unroll
    for (int kk = 0; kk < 8; kk++){
      const int ko = (kk << 5) + (lq << 3);
      short8 aA[4], aB[4];
      #pragma unroll
      for (int m = 0; m < 4; m++){
        aA[m] = *(const short8*)(xsA + (m*16 + l16)*LDX + ko);
        aB[m] = *(const short8*)(xsB + (m*16 + l16)*LDX + ko);
      }
      #pragma unroll
      for (int n = 0; n < 2; n++){
        const int col = (wave << 5) + (n << 4) + l16;
        short8 b = *(const short8*)(Bm + (size_t)col*256 + ko);
        #pragma unroll
        for (int m = 0; m < 4; m++){
          accA[m][n] = MFMA16(aA[m], b, accA[m][n], 0, 0, 0);
          accB[m][n] = MFMA16(aB[m], b, accB[m][n], 0, 0, 0);
        }
      }
    }
    #pragma unroll
    for (int n = 0; n < 2; n++){
      const int col = (wave << 5) + (n << 4) + l16;
      #pragma unroll
      for (int m = 0; m < 4; m++)
        #pragma unroll
        for (int r = 0; r < 4; r++){
          qsA[(m*16 + lq*4 + r)*LDX + col] = f2bf(accA[m][n][r]);
          qsB[(m*16 + lq*4 + r)*LDX + col] = f2bf(accB[m][n][r]);
        }
    }
  }
  __syncthreads();

  // P2+P3 per tile: scores + softmax (lane=(t,s)); axp overwrites G in place
  // (wave reads/writes only its own rows; program-ordered within wave -> safe)
  #pragma unroll
  for (int tile = 0; tile < 2; tile++){
    const unsigned short* xs = tile ? xsB : xsA;
    unsigned short*       qs = tile ? qsB : qsA;
    const int t = lane >> 3, s = lane & 7;
    const unsigned short* Qr = qs + (wave*8 + t)*LDX;        // G row
    const unsigned short* Kr = xs + (wave*8 + s)*LDX;        // xp row
    float e0 = 0.f, e1 = 0.f, e2 = 0.f, e3 = 0.f;
    #pragma unroll
    for (int c = 0; c < 256; c += 8){
      union { short8 v; unsigned int u[4]; } qa, kb;
      qa.v = *(const short8*)(Qr + c);
      kb.v = *(const short8*)(Kr + c);
      e0 = fmaf(lo2f(qa.u[0]), lo2f(kb.u[0]), e0);
      e1 = fmaf(hi2f(qa.u[0]), hi2f(kb.u[0]), e1);
      e2 = fmaf(lo2f(qa.u[1]), lo2f(kb.u[1]), e2);
      e3 = fmaf(hi2f(qa.u[1]), hi2f(kb.u[1]), e3);
      e0 = fmaf(lo2f(qa.u[2]), lo2f(kb.u[2]), e0);
      e1 = fmaf(hi2f(qa.u[2]), hi2f(kb.u[2]), e1);
      e2 = fmaf(lo2f(qa.u[3]), lo2f(kb.u[3]), e2);
      e3 = fmaf(hi2f(qa.u[3]), hi2f(kb.u[3]), e3);
    }
    float e = (e0 + e1) + (e2 + e3);
    e *= 0.0625f;                    // 1/sqrt(256)
    if (s > t) e = -1e30f;           // causal
    float mx = fmaxf(e, __shfl_xor(e, 1));
    mx = fmaxf(mx, __shfl_xor(mx, 2));
    mx = fmaxf(mx, __shfl_xor(mx, 4));
    float p = (s <= t) ? __expf(e - mx) : 0.f;
    float sum = p;
    sum += __shfl_xor(sum, 1);
    sum += __shfl_xor(sum, 2);
    sum += __shfl_xor(sum, 4);
    const float pn = p / sum;        // lane (t,s) holds P[t][s]

    const int c8 = s;
    float o[32];
    #pragma unroll
    for (int j = 0; j < 32; j++) o[j] = 0.f;
    #pragma unroll
    for (int ss = 0; ss < 8; ss++){
      const float w = __shfl(pn, (lane & 56) + ss);
      const unsigned short* Vr = xs + (wave*8 + ss)*LDX + (c8 << 5);
      #pragma unroll
      for (int jj = 0; jj < 4; jj++){
        union { short8 v; unsigned int u[4]; } vv;
        vv.v = *(const short8*)(Vr + jj*8);
        #pragma unroll
        for (int q = 0; q < 4; q++){
          o[jj*8 + 2*q]     = fmaf(w, lo2f(vv.u[q]), o[jj*8 + 2*q]);
          o[jj*8 + 2*q + 1] = fmaf(w, hi2f(vv.u[q]), o[jj*8 + 2*q + 1]);
        }
      }
    }
    unsigned short* Or = qs + (wave*8 + t)*LDX + (c8 << 5);
    #pragma unroll
    for (int j = 0; j < 32; j++) Or[j] = f2bf(o[j]);
  }
  __syncthreads();

  // P4: h1 = relu([axp | xp] @ [PT | W1b]^T + b1) for both tiles; b shared
  {
    const unsigned short* Bp = WT + PT_OFF + (size_t)h*65536;       // [256][256], k<256
    const unsigned short* B1 = WT + W1T_OFF + (size_t)h*W1T_HSTR;   // [256][512], k in [256,512)
    f32x4 accA[4][2], accB[4][2];
    #pragma unroll
    for (int m = 0; m < 4; m++)
      #pragma unroll
      for (int n = 0; n < 2; n++){ accA[m][n] = (f32x4){0.f,0.f,0.f,0.f}; accB[m][n] = (f32x4){0.f,0.f,0.f,0.f}; }
    #pragma unroll
    for (int kk = 0; kk < 8; kk++){           // k<256: A = axp (qs, in-place)
      const int ko = (kk << 5) + (lq << 3);
      short8 aA[4], aB[4];
      #pragma unroll
      for (int m = 0; m < 4; m++){
        aA[m] = *(const short8*)(qsA + (m*16 + l16)*LDX + ko);
        aB[m] = *(const short8*)(qsB + (m*16 + l16)*LDX + ko);
      }
      #pragma unroll
      for (int n = 0; n < 2; n++){
        const int col = (wave << 5) + (n << 4) + l16;
        short8 b = *(const short8*)(Bp + (size_t)col*256 + ko);
        #pragma unroll
        for (int m = 0; m < 4; m++){
          accA[m][n] = MFMA16(aA[m], b, accA[m][n], 0, 0, 0);
          accB[m][n] = MFMA16(aB[m], b, accB[m][n], 0, 0, 0);
        }
      }
    }
    #pragma unroll
    for (int kk = 0; kk < 8; kk++){           // k in [256,512): A = xp (xs), B = W1b half
      const int ko = (kk << 5) + (lq << 3);
      short8 aA[4], aB[4];
      #pragma unroll
      for (int m = 0; m < 4; m++){
        aA[m] = *(const short8*)(xsA + (m*16 + l16)*LDX + ko);
        aB[m] = *(const short8*)(xsB + (m*16 + l16)*LDX + ko);
      }
      #pragma unroll
      for (int n = 0; n < 2; n++){
        const int col = (wave << 5) + (n << 4) + l16;
        short8 b = *(const short8*)(B1 + (size_t)col*512 + 256 + ko);
        #pragma unroll
        for (int m = 0; m < 4; m++){
          accA[m][n] = MFMA16(aA[m], b, accA[m][n], 0, 0, 0);
          accB[m][n] = MFMA16(aB[m], b, accB[m][n], 0, 0, 0);
        }
      }
    }
    __syncthreads();   // all xs (xp) reads done -> safe to overwrite with h1
    #pragma unroll
    for (int n = 0; n < 2; n++){
      const int col = (wave << 5) + (n << 4) + l16;
      const float bv = hb1[(h << 8) + col];
      #pragma unroll
      for (int m = 0; m < 4; m++)
        #pragma unroll
        for (int r = 0; r < 4; r++){
          xsA[(m*16 + lq*4 + r)*LDX + col] = f2bf(fmaxf(accA[m][n][r] + bv, 0.f));
          xsB[(m*16 + lq*4 + r)*LDX + col] = f2bf(fmaxf(accB[m][n][r] + bv, 0.f));
        }
    }
  }
  __syncthreads();

  // P5: feats_h = h1 @ W2T^T + b2 for both tiles; b shared
  {
    const unsigned short* W = WT + W2T_OFF + (size_t)h * W2T_HSTR;
    f32x4 accA[4][2], accB[4][2];
    #pragma unroll
    for (int m = 0; m < 4; m++)
      #pragma unroll
      for (int n = 0; n < 2; n++){ accA[m][n] = (f32x4){0.f,0.f,0.f,0.f}; accB[m][n] = (f32x4){0.f,0.f,0.f,0.f}; }
    #pragma unroll
    for (int kk = 0; kk < 8; kk++){
      const int ko = (kk << 5) + (lq << 3);
      short8 aA[4], aB[4];
      #pragma unroll
      for (int m = 0; m < 4; m++){
        aA[m] = *(const short8*)(xsA + (m*16 + l16)*LDX + ko);
        aB[m] = *(const short8*)(xsB + (m*16 + l16)*LDX + ko);
      }
      #pragma unroll
      for (int n = 0; n < 2; n++){
        const int col = (wave << 5) + (n << 4) + l16;
        short8 b = *(const short8*)(W + (size_t)col*256 + ko);
        #pragma unroll
        for (int m = 0; m < 4; m++){
          accA[m][n] = MFMA16(aA[m], b, accA[m][n], 0, 0, 0);
          accB[m][n] = MFMA16(aB[m], b, accB[m][n], 0, 0, 0);
        }
      }
    }
    #pragma unroll
    for (int n = 0; n < 2; n++){
      const int col = (wave << 5) + (n << 4) + l16;
      const float bv = hb2[(h << 8) + col];
      #pragma unroll
      for (int m = 0; m < 4; m++)
        #pragma unroll
        for (int r = 0; r < 4; r++){
          feats[(size_t)(r0 + m*16 + lq*4 + r)*2048 + (h << 8) + col]      = f2bf(accA[m][n][r] + bv);
          feats[(size_t)(r0 + 64 + m*16 + lq*4 + r)*2048 + (h << 8) + col] = f2bf(accB[m][n][r] + bv);
        }
    }
  }
}

// ==================== output-layer attention ====================
__global__ __launch_bounds__(512, 4) void k_attn2(
    const unsigned short* __restrict__ qkv2, unsigned short* __restrict__ ao)
{
  __shared__ float aw[8][64];
  const int r0   = blockIdx.x * 64;
  const int tid  = threadIdx.x;
  const int wave = tid >> 6;
  const int lane = tid & 63;
  const int g = wave;
  {
    const int t = lane >> 3, s = lane & 7;
    const unsigned short* Qr = qkv2 + (size_t)(r0 + g*8 + t)*768;
    const unsigned short* Kr = qkv2 + (size_t)(r0 + g*8 + s)*768 + 256;
    float e0 = 0.f, e1 = 0.f, e2 = 0.f, e3 = 0.f;
    #pragma unroll
    for (int c = 0; c < 256; c += 8){
      union { short8 v; unsigned int u[4]; } qa, kb;
      qa.v = *(const short8*)(Qr + c);
      kb.v = *(const short8*)(Kr + c);
      e0 = fmaf(lo2f(qa.u[0]), lo2f(kb.u[0]), e0);
      e1 = fmaf(hi2f(qa.u[0]), hi2f(kb.u[0]), e1);
      e2 = fmaf(lo2f(qa.u[1]), lo2f(kb.u[1]), e2);
      e3 = fmaf(hi2f(qa.u[1]), hi2f(kb.u[1]), e3);
      e0 = fmaf(lo2f(qa.u[2]), lo2f(kb.u[2]), e0);
      e1 = fmaf(hi2f(qa.u[2]), hi2f(kb.u[2]), e1);
      e2 = fmaf(lo2f(qa.u[3]), lo2f(kb.u[3]), e2);
      e3 = fmaf(hi2f(qa.u[3]), hi2f(kb.u[3]), e3);
    }
    float e = (e0 + e1) + (e2 + e3);
    e *= 0.0625f;
    if (s > t) e = -1e30f;
    float mx = fmaxf(e, __shfl_xor(e, 1));
    mx = fmaxf(mx, __shfl_xor(mx, 2));
    mx = fmaxf(mx, __shfl_xor(mx, 4));
    float p = (s <= t) ? __expf(e - mx) : 0.f;
    float sum = p;
    sum += __shfl_xor(sum, 1);
    sum += __shfl_xor(sum, 2);
    sum += __shfl_xor(sum, 4);
    aw[g][lane] = p / sum;
  }
  __syncthreads();
  {
    const int t = lane >> 3, c8 = lane & 7;
    float o[32];
    #pragma unroll
    for (int j = 0; j < 32; j++) o[j] = 0.f;
    #pragma unroll
    for (int s = 0; s < 8; s++){
      const float w = aw[g][t*8 + s];
      const unsigned short* Vr = qkv2 + (size_t)(r0 + g*8 + s)*768 + 512 + (c8 << 5);
      #pragma unroll
      for (int jj = 0; jj < 4; jj++){
        union { short8 v; unsigned int u[4]; } vv;
        vv.v = *(const short8*)(Vr + jj*8);
        #pragma unroll
        for (int q = 0; q < 4; q++){
          o[jj*8 + 2*q]     = fmaf(w, lo2f(vv.u[q]), o[jj*8 + 2*q]);
          o[jj*8 + 2*q + 1] = fmaf(w, hi2f(vv.u[q]), o[jj*8 + 2*q + 1]);
        }
      }
    }
    unsigned short* Or = ao + (size_t)(r0 + g*8 + t)*256 + (c8 << 5);
    #pragma unroll
    for (int jj = 0; jj < 4; jj++){
      short8 v;
      #pragma unroll
      for (int q = 0; q < 8; q++) v[q] = (short)f2bf(o[jj*8 + q]);
      *(short8*)(Or + jj*8) = v;
    }
  }
}

// ==================== grouped tiled GEMM with global_load_lds staging ====================
// C_h[M,N] = A_h @ B_h^T. blockIdx.y = h*tilesN + ntile. 128x128 tile, 4 waves,
// BK=64, double-buffered LDS via async global->LDS (linear dest, swizzled source,
// XOR-swizzled frag reads). EPI: 0 = bf16; 1 = bias+relu bf16; 2 = bias f32.
template<int EPI>
__global__ __launch_bounds__(256, 2) void k_gemmg(
    const unsigned short* __restrict__ A1, long long lda1, int K1, long long a1hstr,
    const unsigned short* __restrict__ A2, long long lda2,
    const unsigned short* __restrict__ B, long long ldb, int K, long long bhstr,
    const float* __restrict__ bias, long long biashstr,
    void* __restrict__ Cv, long long ldc, long long chstr,
    int tilesN)
{
  __shared__ __align__(16) unsigned short SM[36864];   // A dbuf 32KB | B dbuf 32KB | (epilogue reuse)
  unsigned short* As = SM;            // [2][8192] elems, linear [128][64] per buf
  unsigned short* Bs = SM + 16384;    // [2][8192]

  const int h  = blockIdx.y / tilesN;
  const int c0 = (blockIdx.y - h*tilesN) * 128;
  A1 += (size_t)h * a1hstr;
  B  += (size_t)h * bhstr;

  const int tid  = threadIdx.x;
  const int wave = tid >> 6, lane = tid & 63;
  const int l16  = lane & 15, lq = lane >> 4;
  const int wm   = wave >> 1, wn = wave & 1;
  const size_t r0 = (size_t)blockIdx.x * 128;

  const int lrow = lane >> 3;                      // 0..7
  const int lcol = ((lane & 7) ^ lrow) << 3;       // swizzled source col (elems)
  const int axor = (l16 & 7) << 3;                 // frag-read XOR (elems)

  f32x4 acc[4][4];
  #pragma unroll
  for (int m = 0; m < 4; m++)
    #pragma unroll
    for (int n = 0; n < 4; n++) acc[m][n] = (f32x4){0.f,0.f,0.f,0.f};

  const int KS = K >> 6;

  // stage one 128x64 A-tile + B-tile into buf (16 x 1KB wave-calls each)
  auto stage = [&](int buf, int k0){
    #pragma unroll
    for (int jj = 0; jj < 4; jj++){
      const int c = wave*4 + jj;                   // chunk 0..15 (8 rows each)
      const int row = c*8 + lrow;
      const unsigned short* ga;
      if (k0 < K1) ga = A1 + (r0 + row)*lda1 + k0 + lcol;
      else         ga = A2 + (r0 + row)*lda2 + (k0 - K1) + lcol;
      load_lds16(ga, As + buf*8192 + c*512);
      const unsigned short* gb = B + (size_t)(c0 + row)*ldb + k0 + lcol;
      load_lds16(gb, Bs + buf*8192 + c*512);
    }
  };

  stage(0, 0);
  __syncthreads();   // drains vmcnt

  int cur = 0;
  for (int s2 = 0; s2 < KS; s2++){
    if (s2 + 1 < KS) stage(cur^1, (s2 + 1) << 6);  // async, in flight under MFMAs
    const unsigned short* Ab = As + cur*8192;
    const unsigned short* Bb = Bs + cur*8192;
    #pragma unroll
    for (int kk = 0; kk < 2; kk++){
      const int cb = (kk << 5) + (lq << 3);
      short8 af[4], bf[4];
      #pragma unroll
      for (int m = 0; m < 4; m++)
        af[m] = *(const short8*)(Ab + (wm*64 + m*16 + l16)*64 + (cb ^ axor));
      #pragma unroll
      for (int n = 0; n < 4; n++)
        bf[n] = *(const short8*)(Bb + (wn*64 + n*16 + l16)*64 + (cb ^ axor));
      #pragma unroll
      for (int n = 0; n < 4; n++)
        #pragma unroll
        for (int m = 0; m < 4; m++)
          acc[m][n] = MFMA16(af[m], bf[n], acc[m][n], 0,0,0);
    }
    __syncthreads();   // drains prefetch + guards buf swap
    cur ^= 1;
  }

  // epilogue: stage C in LDS, coalesced write
  if (EPI == 2){
    float* Cs = (float*)SM;           // [128][130] f32
    float* C = (float*)Cv + (size_t)h * chstr;
    #pragma unroll
    for (int n = 0; n < 4; n++){
      const int col = wn*64 + n*16 + l16;
      const float bv = bias[(size_t)h*biashstr + c0 + col];
      #pragma unroll
      for (int m = 0; m < 4; m++)
        #pragma unroll
        for (int r = 0; r < 4; r++)
          Cs[(wm*64 + m*16 + lq*4 + r)*130 + col] = acc[m][n][r] + bv;
    }
    __syncthreads();
    #pragma unroll
    for (int it = 0; it < 16; it++){
      const int idx = it*256 + tid;
      const int row = idx >> 5, c4 = (idx & 31) << 2;
      *(float4*)(C + (r0 + row)*ldc + c0 + c4) = *(const float4*)(Cs + row*130 + c4);
    }
  } else {
    unsigned short* Cs = SM;          // [128][132] bf16
    unsigned short* C = (unsigned short*)Cv + (size_t)h * chstr;
    #pragma unroll
    for (int n = 0; n < 4; n++){
      const int col = wn*64 + n*16 + l16;
      const float bv = (EPI == 1) ? bias[(size_t)h*biashstr + c0 + col] : 0.f;
      #pragma unroll
      for (int m = 0; m < 4; m++)
        #pragma unroll
        for (int r = 0; r < 4; r++){
          float v = acc[m][n][r] + bv;
          if (EPI == 1) v = fmaxf(v, 0.f);
          Cs[(wm*64 + m*16 + lq*4 + r)*132 + col] = f2bf(v);
        }
    }
    __syncthreads();
    #pragma unroll
    for (int it = 0; it < 8; it++){
      const int idx = it*256 + tid;
      const int row = idx >> 4, c8 = (idx & 15) << 3;
      *(short8*)(C + (r0 + row)*ldc + c0 + c8) = *(const short8*)(Cs + row*132 + c8);
    }
  }
}

extern "C" void kernel_launch(void* const* d_in, const int* in_sizes, int n_in,
                              void* d_out, int out_size, void* d_ws, size_t ws_size,
                              hipStream_t stream) {
  (void)n_in; (void)out_size;
  const float* x    = (const float*)d_in[0];
  const float* pos  = (const float*)d_in[1];
  const float* hWq  = (const float*)d_in[2];
  const float* hWk  = (const float*)d_in[3];
  const float* hWv  = (const float*)d_in[4];
  const float* hW1  = (const float*)d_in[5];
  const float* hb1  = (const float*)d_in[6];
  const float* hW2  = (const float*)d_in[7];
  const float* hb2  = (const float*)d_in[8];
  const float* oWq  = (const float*)d_in[9];
  const float* oWk  = (const float*)d_in[10];
  const float* oWv  = (const float*)d_in[11];
  const float* oW1  = (const float*)d_in[12];
  const float* ob1  = (const float*)d_in[13];
  const float* oW2  = (const float*)d_in[14];
  const float* ob2  = (const float*)d_in[15];

  unsigned short* WT  = (unsigned short*)d_ws;
  unsigned short* xp  = (unsigned short*)((char*)d_ws + XP_OFFB);
  float* out = (float*)d_out;

  const long long BT = in_sizes[0] / 256;   // 131072

  // chunk sizing: feats + qkv2 + ao + h1 rings = R*6656 bytes; keep L3-resident
  const size_t capB = (ws_size > FEATS_OFFB) ? (ws_size - FEATS_OFFB) : 0;
  long long R = (long long)(capB / 6656);
  if (R > 16384) R = 16384;
  if (R > BT) R = BT;
  R &= ~127LL;
  if (R < 128) R = 128;

  unsigned short* feats = (unsigned short*)((char*)d_ws + FEATS_OFFB);
  unsigned short* qkv2  = (unsigned short*)((char*)feats + (size_t)R*4096);
  unsigned short* ao    = (unsigned short*)((char*)qkv2  + (size_t)R*1536);
  unsigned short* h1o   = (unsigned short*)((char*)ao    + (size_t)R*512);

  // ---- prep: transposes, casts, weight-product GEMMs ----
  k_transpose<<<dim3(512,8),  256, 0, stream>>>(hW1, WT + W1T_OFF,            512, 256, 131072, 131072);
  k_transpose<<<dim3(256,8),  256, 0, stream>>>(hW2, WT + W2T_OFF,            256, 256, 65536, 65536);
  k_transpose<<<dim3(2048,1), 256, 0, stream>>>(oWq, WT + OQKV_OFF,           2048, 256, 0, 0);
  k_transpose<<<dim3(2048,1), 256, 0, stream>>>(oWk, WT + OQKV_OFF + 524288,  2048, 256, 0, 0);
  k_transpose<<<dim3(2048,1), 256, 0, stream>>>(oWv, WT + OQKV_OFF + 1048576, 2048, 256, 0, 0);
  k_transpose<<<dim3(2304,1), 256, 0, stream>>>(oW1, WT + OW1_OFF,            2304, 256, 0, 0);
  k_transpose<<<dim3(256,1),  256, 0, stream>>>(oW2, WT + OW2_OFF,            256, 256, 0, 0);
  k_cast<<<512, 256, 0, stream>>>(hWq, WT + WQC_OFF);
  k_cast<<<512, 256, 0, stream>>>(hWk, WT + WKC_OFF);
  k_cast<<<512, 256, 0, stream>>>(hWv, WT + WVC_OFF);

  // MT_h[m][i] = sum_j Wk[m][j] Wq[i][j]
  k_gemmg<0><<<dim3(2, 16), 256, 0, stream>>>(
      WT + WKC_OFF, 256, 1<<30, 65536, WT + WKC_OFF, 256,
      WT + WQC_OFF, 256, 256, 65536, nullptr, 0,
      WT + MT_OFF, 256, 65536, 2);

  // PT_h[j][m] = sum_d W1a[d][j] Wv[m][d]
  k_gemmg<0><<<dim3(2, 16), 256, 0, stream>>>(
      WT + W1T_OFF, 512, 1<<30, W1T_HSTR, WT + W1T_OFF, 512,
      WT + WVC_OFF, 256, 256, 65536, nullptr, 0,
      WT + PT_OFF, 256, 65536, 2);

  k_xp<<<(int)(BT/8), 256, 0, stream>>>(x, pos, xp);

  for (long long base = 0; base < BT; base += R) {
    const long long Rc = (BT - base < R) ? (BT - base) : R;
    const int mt64  = (int)(Rc / 64);
    const int mt128 = (int)(Rc / 128);

    k_head<<<dim3(mt128, 8), 512, 0, stream>>>(xp + base*256, WT, hb1, hb2, feats);

    // QKV2: A = feats [R][2048], K=2048
    k_gemmg<0><<<dim3(mt128, 6), 256, 0, stream>>>(
        feats, 2048, 1<<30, 0, feats, 2048,
        WT + OQKV_OFF, 2048, 2048, 0, nullptr, 0, qkv2, 768, 0, 6);

    k_attn2<<<mt64, 512, 0, stream>>>(qkv2, ao);

    // FFN1o: A = [ao | feats], K=2304
    k_gemmg<1><<<dim3(mt128, 2), 256, 0, stream>>>(
        ao, 256, 256, 0, feats, 2048,
        WT + OW1_OFF, 2304, 2304, 0, ob1, 0, h1o, 256, 0, 2);

    // FFN2o: A = h1o, K=256
    k_gemmg<2><<<dim3(mt128, 2), 256, 0, stream>>>(
        h1o, 256, 1<<30, 0, h1o, 256,
        WT + OW2_OFF, 256, 256, 0, ob2, 0, out + base*256, 256, 0, 2);
  }
}